// Round 13
// baseline (148.006 us; speedup 1.0000x reference)
//
#include <hip/hip_runtime.h>
#include <stdint.h>

#define TT 4096
#define HIDD 1024

typedef __attribute__((ext_vector_type(4))) float f32x4;
typedef __attribute__((ext_vector_type(16))) float f32x16;
typedef __attribute__((ext_vector_type(8))) short s16x8;

static constexpr float kEps = 1e-6f;
static constexpr float kCsc = 0.125f * 1.44269504088896f;  // scale * log2(e), folded into q

// ---- workspace layout (bytes); lifetimes ----
// hs_swz [convert->gemm_qkv], wqkv [convert->gemm_qkv]  (both die before obuf memset)
static constexpr size_t OFF_HS   = 0;          // bf16 hs swz [4096][1024] 8 MB
static constexpr size_t OFF_WQKV = 8388608;    // bf16 WqkvT  [1536][1024] 3 MB
static constexpr size_t OFF_OBUF = 0;          // f32 O partial [4096][1024] 16.78 MB (overlays hs+wqkv)
static constexpr size_t OFF_LBUF = 16777216;   // f32 l partial [16][4096] 256 KB
static constexpr size_t OFF_WO   = 17039360;   // bf16 WoT [1024][1024] 2 MB (must survive to gemm2)
static constexpr size_t OFF_Q    = 19136512;   // bf16 q [16][4096][64] 8 MB
static constexpr size_t OFF_K    = 27525120;   // bf16 k swz [4][4096][64] 2 MB
static constexpr size_t OFF_VT   = 29622272;   // bf16 vT swz [4][64][4096] 2 MB
static constexpr size_t OFF_O    = 31719424;   // bf16 attn-out swz [4096][1024] 8 MB  (end 40.1 MB)

__device__ __forceinline__ unsigned int pk_bf16(float a, float b) {
  union { float f; unsigned int u; } x, y;
  x.f = a; y.f = b;
  unsigned int lo = (x.u + 0x7fffu + ((x.u >> 16) & 1u)) >> 16;
  unsigned int hi = (y.u + 0x7fffu + ((y.u >> 16) & 1u)) >> 16;
  return (lo & 0xffffu) | (hi << 16);
}
__device__ __forceinline__ unsigned int cvtpk(float lo, float hi) {
  unsigned int r;
  asm("v_cvt_pk_bf16_f32 %0, %1, %2" : "=v"(r) : "v"(lo), "v"(hi));
  return r;
}
__device__ __forceinline__ void gload16(const void* g, void* l) {
  __builtin_amdgcn_global_load_lds(
      (const __attribute__((address_space(1))) unsigned int*)g,
      (__attribute__((address_space(3))) unsigned int*)l, 16, 0, 0);
}

// hs fp32 [T][1024] -> bf16 swizzled (16B chunk index XORed by row&7 within 64-elem groups)
__global__ void k_convert_hs(const float* __restrict__ hs, unsigned short* __restrict__ out) {
  int idx = blockIdx.x * 256 + threadIdx.x;  // T*128
  int t = idx >> 7, kc = idx & 127;
  const float4* src = (const float4*)(hs + (size_t)t * HIDD + kc * 8);
  float4 a = src[0], b = src[1];
  int kcs = (kc & ~7) | ((kc & 7) ^ (t & 7));
  uint4 w;
  w.x = pk_bf16(a.x, a.y); w.y = pk_bf16(a.z, a.w);
  w.z = pk_bf16(b.x, b.y); w.w = pk_bf16(b.z, b.w);
  *(uint4*)(out + (size_t)t * HIDD + kcs * 8) = w;
}

// All four weight matrices: fp32 [1024][ncols] -> bf16 W^T [ncols][1024] swizzled by n&7
__global__ void k_convert_w_all(const float* __restrict__ Wq, const float* __restrict__ Wk,
                                const float* __restrict__ Wv, const float* __restrict__ Wo,
                                unsigned short* __restrict__ wqkv, unsigned short* __restrict__ wo_t) {
  int b = blockIdx.x, tid = threadIdx.x;
  const float* W; unsigned short* outT; int nshift, idx;
  if (b < 512)      { W = Wq; outT = wqkv;                nshift = 10; idx = b * 256 + tid; }
  else if (b < 640) { W = Wk; outT = wqkv + 1024 * 1024;  nshift = 8;  idx = (b - 512) * 256 + tid; }
  else if (b < 768) { W = Wv; outT = wqkv + 1280 * 1024;  nshift = 8;  idx = (b - 640) * 256 + tid; }
  else              { W = Wo; outT = wo_t;                nshift = 10; idx = (b - 768) * 256 + tid; }
  int ncols = 1 << nshift;
  int kc = idx >> nshift, n = idx & (ncols - 1);
  float v[8];
#pragma unroll
  for (int e = 0; e < 8; ++e) v[e] = W[(size_t)(kc * 8 + e) * ncols + n];
  int kcs = (kc & ~7) | ((kc & 7) ^ (n & 7));
  uint4 w;
  w.x = pk_bf16(v[0], v[1]); w.y = pk_bf16(v[2], v[3]);
  w.z = pk_bf16(v[4], v[5]); w.w = pk_bf16(v[6], v[7]);
  *(uint4*)(outT + (size_t)n * HIDD + kcs * 8) = w;
}

// Fused QKV GEMM + RMSNorm + RoPE + bf16 layout conversion (R12, verified).
__global__ __launch_bounds__(256) void k_gemm_qkv(const unsigned short* __restrict__ A,
                                                  const unsigned short* __restrict__ Bt,
                                                  const float* __restrict__ cosb,
                                                  const float* __restrict__ sinb,
                                                  const float* __restrict__ qw,
                                                  const float* __restrict__ kw,
                                                  unsigned short* __restrict__ qo,
                                                  unsigned short* __restrict__ ko,
                                                  unsigned short* __restrict__ vt) {
  __shared__ __attribute__((aligned(16))) char smem[49152];
  const int K = HIDD;
  const int tid = threadIdx.x;
  const int m0 = blockIdx.y * 128, slot = blockIdx.x, n0 = slot * 64;
  const int wid = tid >> 6, lane = tid & 63;
  const int g = lane >> 4, qi = lane & 15;
  const int wr = wid >> 1, wc = wid & 1;
  const int srow = lane >> 3, schk = lane & 7;
  f32x4 acc[4][2] = {};
  const int nkt = K >> 6;

  auto STAGE = [&](int b, int k0) {
#pragma unroll
    for (int j = 0; j < 4; ++j) {
      int ra = j * 32 + wid * 8 + srow;
      gload16(A + (size_t)(m0 + ra) * K + k0 + schk * 8,
              smem + b * 16384 + j * 4096 + (wid << 10));
    }
#pragma unroll
    for (int j = 0; j < 2; ++j) {
      int rb = j * 32 + wid * 8 + srow;
      gload16(Bt + (size_t)(n0 + rb) * K + k0 + schk * 8,
              smem + 32768 + b * 8192 + j * 4096 + (wid << 10));
    }
  };

  STAGE(0, 0);
  __syncthreads();
  int cur = 0;
  for (int kt = 0; kt < nkt; ++kt) {
    if (kt + 1 < nkt) STAGE(cur ^ 1, (kt + 1) << 6);
#pragma unroll
    for (int kh = 0; kh < 2; ++kh) {
      s16x8 af[4], bq[2];
#pragma unroll
      for (int i = 0; i < 4; ++i) {
        int rA = wr * 64 + i * 16 + qi;
        af[i] = *(const s16x8*)(smem + cur * 16384 + rA * 128 + ((((kh << 2) | g) ^ (rA & 7)) << 4));
      }
#pragma unroll
      for (int jn = 0; jn < 2; ++jn) {
        int rB = wc * 32 + jn * 16 + qi;
        bq[jn] = *(const s16x8*)(smem + 32768 + cur * 8192 + rB * 128 + ((((kh << 2) | g) ^ (rB & 7)) << 4));
      }
      __builtin_amdgcn_s_setprio(1);
#pragma unroll
      for (int i = 0; i < 4; ++i)
#pragma unroll
        for (int jn = 0; jn < 2; ++jn)
          acc[i][jn] = __builtin_amdgcn_mfma_f32_16x16x32_bf16(af[i], bq[jn], acc[i][jn], 0, 0, 0);
      __builtin_amdgcn_s_setprio(0);
    }
    __syncthreads();
    cur ^= 1;
  }

  // ---- epilogue ----
  float* Cs = (float*)smem;                 // [128][66] f32
#pragma unroll
  for (int i = 0; i < 4; ++i)
#pragma unroll
    for (int jn = 0; jn < 2; ++jn) {
      int row = wr * 64 + i * 16 + g * 4;
      int col = wc * 32 + jn * 16 + qi;
#pragma unroll
      for (int r = 0; r < 4; ++r)
        Cs[(row + r) * 66 + col] = acc[i][jn][r];
    }
  __syncthreads();

  if (slot < 20) {
    const int lr = tid >> 1, hf = tid & 1;
    const int t = m0 + lr;
    const float* self_p = Cs + lr * 66 + hf * 32;
    const float* oth_p  = Cs + lr * 66 + (1 - hf) * 32;
    float ss = 0.0f;
#pragma unroll
    for (int e = 0; e < 32; ++e) { float v = self_p[e]; ss += v * v; }
    ss += __shfl_xor(ss, 1);
    const float rms = rsqrtf(ss * (1.0f / 64.0f) + kEps);
    const float* wvec = (slot < 16) ? qw : kw;
    const float outscale = (slot < 16) ? kCsc : 1.0f;
    unsigned int u[16];
#pragma unroll
    for (int ee = 0; ee < 16; ++ee) {
      float o2[2];
#pragma unroll
      for (int p = 0; p < 2; ++p) {
        int e = 2 * ee + p;
        float c = cosb[t * 32 + e];
        float s = sinb[t * 32 + e];
        float self = self_p[e] * rms * wvec[hf * 32 + e];
        float oth  = oth_p[e]  * rms * wvec[(1 - hf) * 32 + e];
        float r = hf ? (oth * s + self * c) : (self * c - oth * s);
        o2[p] = r * outscale;
      }
      u[ee] = cvtpk(o2[0], o2[1]);
    }
    if (slot < 16) {
      unsigned short* base = qo + ((size_t)slot * TT + t) * 64 + hf * 32;
#pragma unroll
      for (int cidx = 0; cidx < 4; ++cidx) {
        uint4 w; w.x = u[cidx * 4]; w.y = u[cidx * 4 + 1]; w.z = u[cidx * 4 + 2]; w.w = u[cidx * 4 + 3];
        *(uint4*)(base + cidx * 8) = w;
      }
    } else {
      const int hv = slot - 16;
      unsigned short* base = ko + ((size_t)hv * TT + t) * 64;
#pragma unroll
      for (int cidx = 0; cidx < 4; ++cidx) {
        int gc = hf * 4 + cidx;
        uint4 w; w.x = u[cidx * 4]; w.y = u[cidx * 4 + 1]; w.z = u[cidx * 4 + 2]; w.w = u[cidx * 4 + 3];
        *(uint4*)(base + (gc ^ (t & 7)) * 8) = w;
      }
    }
  } else {
    const int hv = slot - 20;
#pragma unroll
    for (int tt = 0; tt < 2; ++tt)
#pragma unroll
      for (int jj = 0; jj < 2; ++jj) {
        int idx = jj * 256 + tid;
        int d = idx >> 3, tc = idx & 7;
        uint4 w;
        w.x = cvtpk(Cs[(tt * 64 + tc * 8 + 0) * 66 + d], Cs[(tt * 64 + tc * 8 + 1) * 66 + d]);
        w.y = cvtpk(Cs[(tt * 64 + tc * 8 + 2) * 66 + d], Cs[(tt * 64 + tc * 8 + 3) * 66 + d]);
        w.z = cvtpk(Cs[(tt * 64 + tc * 8 + 4) * 66 + d], Cs[(tt * 64 + tc * 8 + 5) * 66 + d]);
        w.w = cvtpk(Cs[(tt * 64 + tc * 8 + 6) * 66 + d], Cs[(tt * 64 + tc * 8 + 7) * 66 + d]);
        int tcs = tc ^ (d & 7);
        *(uint4*)(vt + ((size_t)hv * 64 + d) * TT + m0 + tt * 64 + tcs * 8) = w;
      }
  }
}

// C[M][N] = A[M][K] * Bt[N][K]^T ; 128x64 tile, BK=64, 4 waves, dbuf LDS (output proj).
__global__ __launch_bounds__(256) void k_gemm(const unsigned short* __restrict__ A,
                                              const unsigned short* __restrict__ Bt,
                                              float* __restrict__ C, int M, int N, int K) {
  __shared__ __attribute__((aligned(16))) unsigned short As[2][128 * 64];
  __shared__ __attribute__((aligned(16))) unsigned short Bs[2][64 * 64];
  const int tid = threadIdx.x;
  const int m0 = blockIdx.y * 128, n0 = blockIdx.x * 64;
  const int wid = tid >> 6, lane = tid & 63;
  const int g = lane >> 4, qi = lane & 15;
  const int wr = wid >> 1, wc = wid & 1;
  const int srow = lane >> 3, schk = lane & 7;
  f32x4 acc[4][2] = {};
  const int nkt = K >> 6;

  auto STAGE = [&](int b, int k0) {
#pragma unroll
    for (int j = 0; j < 4; ++j) {
      int ra = j * 32 + wid * 8 + srow;
      gload16(A + (size_t)(m0 + ra) * K + k0 + schk * 8,
              (char*)&As[b][0] + j * 4096 + (wid << 10));
    }
#pragma unroll
    for (int j = 0; j < 2; ++j) {
      int rb = j * 32 + wid * 8 + srow;
      gload16(Bt + (size_t)(n0 + rb) * K + k0 + schk * 8,
              (char*)&Bs[b][0] + j * 4096 + (wid << 10));
    }
  };

  STAGE(0, 0);
  __syncthreads();
  int cur = 0;
  for (int kt = 0; kt < nkt; ++kt) {
    if (kt + 1 < nkt) STAGE(cur ^ 1, (kt + 1) << 6);
#pragma unroll
    for (int kh = 0; kh < 2; ++kh) {
      s16x8 af[4], bq[2];
#pragma unroll
      for (int i = 0; i < 4; ++i) {
        int rA = wr * 64 + i * 16 + qi;
        af[i] = *(const s16x8*)((const char*)&As[cur][0] + rA * 128 + ((((kh << 2) | g) ^ (rA & 7)) << 4));
      }
#pragma unroll
      for (int jn = 0; jn < 2; ++jn) {
        int rB = wc * 32 + jn * 16 + qi;
        bq[jn] = *(const s16x8*)((const char*)&Bs[cur][0] + rB * 128 + ((((kh << 2) | g) ^ (rB & 7)) << 4));
      }
      __builtin_amdgcn_s_setprio(1);
#pragma unroll
      for (int i = 0; i < 4; ++i)
#pragma unroll
        for (int jn = 0; jn < 2; ++jn)
          acc[i][jn] = __builtin_amdgcn_mfma_f32_16x16x32_bf16(af[i], bq[jn], acc[i][jn], 0, 0, 0);
      __builtin_amdgcn_s_setprio(0);
    }
    __syncthreads();
    cur ^= 1;
  }
#pragma unroll
  for (int i = 0; i < 4; ++i)
#pragma unroll
    for (int jn = 0; jn < 2; ++jn) {
      int row = m0 + wr * 64 + i * 16 + g * 4;
      int col = n0 + wc * 32 + jn * 16 + qi;
#pragma unroll
      for (int r = 0; r < 4; ++r)
        C[(size_t)(row + r) * N + col] = acc[i][jn][r];
    }
}

// Flash attention, causal GQA — 32q/wave 32x32x16 MFMA (R10-verified math), with
// PROVABLY UNIFORM blocks: band = 128 q-rows; block = 4 waves x 32q; block handles
// band-pair (31-j long, j short) sequentially, each with HALF its kv range:
// (32-j) + (j+1) = 33 steps for every one of the 512 blocks. Fixed-max softmax makes
// kv-halves independent: each phase flushes unnormalized O (f32 atomicAdd, exactly 2
// commutative adds/address -> deterministic) + l; k_norm divides at the end.
// In-register P via permlane32_swap. LDS padded to 56KB -> exactly 2 blocks/CU.
__global__ __launch_bounds__(256, 2) void k_attn(const unsigned short* __restrict__ q,
                                                 const unsigned short* __restrict__ kk,
                                                 const unsigned short* __restrict__ vt,
                                                 float* __restrict__ obuf,
                                                 float* __restrict__ lbuf) {
  __shared__ __attribute__((aligned(16))) char smem[57344];  // K dbuf 16K @0, V dbuf 16K @16384, pad
  const int tid = threadIdx.x;
  const int wid = tid >> 6, lane = tid & 63;
  const int ln31 = lane & 31, hi = lane >> 5;
  const int bid = blockIdx.x;
  const int xcd = bid & 7;
  const int rdec = bid >> 3;                 // [0,64)
  const int head = xcd * 2 + (rdec >> 5);    // 2 heads per XCD (one KV group, L2-resident)
  const int rr = rdec & 31;
  const int j = rr >> 1, half = rr & 1;
  const int hv = head >> 2;

  auto STAGE = [&](int b, int kvt) {
    const int kv0 = kvt * 64;
#pragma unroll
    for (int p = 0; p < 2; ++p) {
      int c = tid + p * 256;
      int row = c >> 3, ch = c & 7;
      gload16(kk + ((size_t)hv * TT + kv0 + row) * 64 + ch * 8,
              smem + b * 8192 + c * 16);
      gload16(vt + ((size_t)hv * 64 + row) * TT + kv0 + ch * 8,
              smem + 16384 + b * 8192 + c * 16);
    }
  };

#pragma unroll
  for (int phase = 0; phase < 2; ++phase) {
    const int band = phase ? j : (31 - j);
    const int len  = phase ? (j + 1) : (32 - j);
    const int kvlo = half * len;
    const int qb = band * 128 + wid * 32;     // this wave's 32 q-rows
    const int diagT = qb >> 6;                // wave's diagonal kv tile
    const int qg = qb + ln31;

    s16x8 qf[4];
#pragma unroll
    for (int ks = 0; ks < 4; ++ks)
      qf[ks] = *(const s16x8*)(q + ((size_t)head * TT + qb + ln31) * 64 + ks * 16 + hi * 8);

    f32x16 oacc[2] = {};
    float lp0 = 0.0f, lp1 = 0.0f;

    STAGE(0, kvlo);
    __syncthreads();
    int cur = 0;
    for (int ss = 0; ss < len; ++ss) {
      if (ss + 1 < len) STAGE(cur ^ 1, kvlo + ss + 1);
      const int kvt = kvlo + ss;
      if (kvt <= diagT) {
        const int kv0 = kvt * 64;
        const char* Kb = smem + cur * 8192;
        const char* Vb = smem + 16384 + cur * 8192;
        f32x16 sacc[2] = {};
#pragma unroll
        for (int T = 0; T < 2; ++T) {
#pragma unroll
          for (int ks = 0; ks < 4; ++ks) {
            int row = T * 32 + ln31;
            s16x8 kf = *(const s16x8*)(Kb + row * 128 + (((2 * ks + hi) ^ (row & 7)) << 4));
            sacc[T] = __builtin_amdgcn_mfma_f32_32x32x16_bf16(kf, qf[ks], sacc[T], 0, 0, 0);
          }
        }
        float pv[32];
        const bool diag = (kvt == diagT);
#pragma unroll
        for (int T = 0; T < 2; ++T)
#pragma unroll
          for (int r = 0; r < 16; ++r) {
            float v = sacc[T][r];
            if (diag) {
              int kvg = kv0 + T * 32 + (r & 3) + 8 * (r >> 2) + 4 * hi;
              if (kvg > qg) v = -1e30f;
            }
            float e = exp2f(v);
            pv[T * 16 + r] = e;
            if (r & 1) lp1 += e; else lp0 += e;
          }
        s16x8 pa[4];
#pragma unroll
        for (int ks = 0; ks < 4; ++ks) {
          const float* pg = pv + ks * 8;
          unsigned w0 = cvtpk(pg[0], pg[1]);
          unsigned w1 = cvtpk(pg[2], pg[3]);
          unsigned w2 = cvtpk(pg[4], pg[5]);
          unsigned w3 = cvtpk(pg[6], pg[7]);
          asm("v_permlane32_swap_b32 %0, %1" : "+v"(w0), "+v"(w2));
          asm("v_permlane32_swap_b32 %0, %1" : "+v"(w1), "+v"(w3));
          union { uint4 u4; s16x8 v8; } cc;
          cc.u4.x = w0; cc.u4.y = w1; cc.u4.z = w2; cc.u4.w = w3;
          pa[ks] = cc.v8;
        }
#pragma unroll
        for (int D = 0; D < 2; ++D) {
#pragma unroll
          for (int ks = 0; ks < 4; ++ks) {
            int row = D * 32 + ln31;
            s16x8 vf = *(const s16x8*)(Vb + row * 128 + (((2 * ks + hi) ^ (row & 7)) << 4));
            oacc[D] = __builtin_amdgcn_mfma_f32_32x32x16_bf16(pa[ks], vf, oacc[D], 0, 0, 0);
          }
        }
      }
      __syncthreads();
      cur ^= 1;
    }
    // flush unnormalized partials (exactly 2 contributions per address across the grid)
    float lfull = lp0 + lp1;
    lfull += __shfl_xor(lfull, 32);
    if (hi == 0)
      unsafeAtomicAdd(lbuf + (size_t)head * TT + qb + ln31, lfull);
#pragma unroll
    for (int r = 0; r < 16; ++r) {
      int qoff = (r & 3) + 8 * (r >> 2) + 4 * hi;
#pragma unroll
      for (int D = 0; D < 2; ++D)
        unsafeAtomicAdd(obuf + (size_t)(qb + qoff) * 1024 + head * 64 + D * 32 + ln31, oacc[D][r]);
    }
  }
}

// O = obuf / l, packed to bf16 obf (chunk-swizzled [t][1024], gemm2 A layout)
__global__ void k_norm(const float* __restrict__ obuf, const float* __restrict__ lbuf,
                       unsigned short* __restrict__ obf) {
  int idx = blockIdx.x * 256 + threadIdx.x;   // T*128
  int t = idx >> 7, kc = idx & 127;
  const float4* src = (const float4*)(obuf + (size_t)t * 1024 + kc * 8);
  float inv = 1.0f / lbuf[(size_t)(kc >> 3) * TT + t];
  float4 a = src[0], b = src[1];
  uint4 w;
  w.x = cvtpk(a.x * inv, a.y * inv); w.y = cvtpk(a.z * inv, a.w * inv);
  w.z = cvtpk(b.x * inv, b.y * inv); w.w = cvtpk(b.z * inv, b.w * inv);
  int kcs = (kc & ~7) | ((kc & 7) ^ (t & 7));
  *(uint4*)(obf + (size_t)t * 1024 + kcs * 8) = w;
}

extern "C" void kernel_launch(void* const* d_in, const int* in_sizes, int n_in,
                              void* d_out, int out_size, void* d_ws, size_t ws_size,
                              hipStream_t stream) {
  const float* hs   = (const float*)d_in[0];
  const float* cosb = (const float*)d_in[1];
  const float* sinb = (const float*)d_in[2];
  const float* Wq   = (const float*)d_in[3];
  const float* Wk   = (const float*)d_in[4];
  const float* Wv   = (const float*)d_in[5];
  const float* Wo   = (const float*)d_in[6];
  const float* qw   = (const float*)d_in[7];
  const float* kw   = (const float*)d_in[8];
  char* ws = (char*)d_ws;
  unsigned short* hs_swz = (unsigned short*)(ws + OFF_HS);
  unsigned short* wqkv   = (unsigned short*)(ws + OFF_WQKV);
  float*          obuf   = (float*)(ws + OFF_OBUF);
  float*          lbuf   = (float*)(ws + OFF_LBUF);
  unsigned short* wo_t   = (unsigned short*)(ws + OFF_WO);
  unsigned short* qbf    = (unsigned short*)(ws + OFF_Q);
  unsigned short* kbf    = (unsigned short*)(ws + OFF_K);
  unsigned short* vtb    = (unsigned short*)(ws + OFF_VT);
  unsigned short* obf    = (unsigned short*)(ws + OFF_O);

  k_convert_hs<<<2048, 256, 0, stream>>>(hs, hs_swz);
  k_convert_w_all<<<1280, 256, 0, stream>>>(Wq, Wk, Wv, Wo, wqkv, wo_t);
  k_gemm_qkv<<<dim3(24, 32), 256, 0, stream>>>(hs_swz, wqkv, cosb, sinb, qw, kw, qbf, kbf, vtb);
  hipMemsetAsync(obuf, 0, (size_t)4096 * 1024 * 4, stream);   // overlays dead hs_swz/wqkv
  hipMemsetAsync(lbuf, 0, (size_t)16 * 4096 * 4, stream);
  k_attn<<<512, 256, 0, stream>>>(qbf, kbf, vtb, obuf, lbuf);
  k_norm<<<2048, 256, 0, stream>>>(obuf, lbuf, obf);
  k_gemm<<<dim3(16, 32), 256, 0, stream>>>(obf, wo_t, (float*)d_out, 4096, 1024, 1024);
}